// Round 8
// baseline (51.399 us; speedup 1.0000x reference)
//
#include <hip/hip_runtime.h>
#include <hip/hip_fp16.h>

// LSTM_8589935226: B=4194304 independent LSTMs, T=4, I=1, H=2, C=1.
// Round 8 = Round 7 with the compile fix: ROCm 7.2 lacks __hmin2/__hmax2/
// __hneg2 — packed clamp implemented via __builtin_elementwise_min/max on the
// _Float16 ext_vector payload (maps to v_pk_min_f16/v_pk_max_f16).
// Zero exp ops: [5/4] Pade tanh rationals in packed f16; sigmoid(u) =
// 0.5 + 0.5*tanh(u/2) with the 0.5 arg-scale folded into prep weights;
// one v_rcp_f16 per activation pair (pair-Montgomery, den <= 12.2).
// Trans/elem 48 -> 19. Model: busy/wave ~2294 -> ~1790 cyc -> ~35 us.

typedef _Float16 hv2 __attribute__((ext_vector_type(2)));

__device__ __forceinline__ __half2 bc(float f) {  // broadcast const -> half2
    return __half2half2(__float2half_rn(f));
}

// packed clamp to [-lim, +lim]
__device__ __forceinline__ __half2 clamp2(__half2 x, __half2 lim, __half2 nlim) {
    hv2 xv = ((__half2_raw)x).data;
    hv2 lv = ((__half2_raw)lim).data;
    hv2 nv = ((__half2_raw)nlim).data;
    xv = __builtin_elementwise_min(xv, lv);
    xv = __builtin_elementwise_max(xv, nv);
    __half2_raw r; r.data = xv;
    return r;
}

// ws layout: __half2 w[16] at offset 0:
//   w[0..3]  = WI pair p (gate pair p = rows 2p,2p+1), arg-scaled
//   w[4..7]  = WH0 pair p
//   w[8..11] = WH1 pair p
//   w[12..15]= BB  pair p
// floats at byte offset 128: wf0, wf1, bf
__global__ void lstm_prep(const float* __restrict__ W_ih,
                          const float* __restrict__ W_hh,
                          const float* __restrict__ b_ih,
                          const float* __restrict__ b_hh,
                          const float* __restrict__ W_fc,
                          const float* __restrict__ b_fc,
                          void* __restrict__ wsv)
{
    __half2* wsh = (__half2*)wsv;
    float* wsf = (float*)((char*)wsv + 128);
    const int p = threadIdx.x;
    if (p < 4) {
        // gate pairs: p=0 i(0,1), p=1 f(2,3), p=2 g(4,5), p=3 o(6,7)
        // sigmoid pairs scaled by 0.5 (tanh(u/2) form); g pair unscaled.
        const float s = (p == 2) ? 1.0f : 0.5f;
        const int g0 = 2 * p, g1 = 2 * p + 1;
        wsh[p]      = __floats2half2_rn(W_ih[g0] * s, W_ih[g1] * s);
        wsh[4 + p]  = __floats2half2_rn(W_hh[2 * g0] * s, W_hh[2 * g1] * s);
        wsh[8 + p]  = __floats2half2_rn(W_hh[2 * g0 + 1] * s, W_hh[2 * g1 + 1] * s);
        wsh[12 + p] = __floats2half2_rn((b_ih[g0] + b_hh[g0]) * s,
                                        (b_ih[g1] + b_hh[g1]) * s);
    } else if (p == 4) {
        wsf[0] = W_fc[0];
        wsf[1] = W_fc[1];
        wsf[2] = b_fc[0];
    }
}

// Pair-shared reciprocal: inv(d) elementwise via one v_rcp_f16.
// d0*d1 <= 12.2^2 = 149, fits f16. 1/d0 = r*d1, 1/d1 = r*d0.
__device__ __forceinline__ __half2 pair_inv(__half2 d) {
    const __half m = __hmul(__low2half(d), __high2half(d));
    const __half r = hrcp(m);
    const __half2 sw = __halves2half2(__high2half(d), __low2half(d));
    return __hmul2(__half2half2(r), sw);
}

// tanh on both halves: clamp |x|<=4, normalized [5/4] Pade
//   tanh(x) ~ x*(1 + t*(105/945 + t/945)) / (1 + t*(420/945 + 15/945*t))
// max abs err ~2.3e-3 (near |x|=4), t = x^2 <= 16, den <= 12.2.
__device__ __forceinline__ __half2 tanh2(__half2 x, __half2 L, __half2 NL) {
    x = clamp2(x, L, NL);
    const __half2 t = __hmul2(x, x);
    __half2 n = __hfma2(t, bc(1.05820106e-3f), bc(0.111111111f));
    n = __hfma2(t, n, bc(1.0f));
    n = __hmul2(n, x);
    __half2 d = __hfma2(t, bc(0.015873016f), bc(0.444444444f));
    d = __hfma2(t, d, bc(1.0f));
    return __hmul2(n, pair_inv(d));
}

// One timestep t>=1. h, c are half2 (channel 0 in lo, 1 in hi).
__device__ __forceinline__ void lstm_step(__half2 xb, __half2& h, __half2& c,
                                          const __half2* __restrict__ w,
                                          __half2 L, __half2 NL)
{
    const __half2 h0 = __low2half2(h);
    const __half2 h1 = __high2half2(h);
    const __half2 pi = __hfma2(xb, w[0], __hfma2(h0, w[4], __hfma2(h1, w[8],  w[12])));
    const __half2 pf = __hfma2(xb, w[1], __hfma2(h0, w[5], __hfma2(h1, w[9],  w[13])));
    const __half2 pg = __hfma2(xb, w[2], __hfma2(h0, w[6], __hfma2(h1, w[10], w[14])));
    const __half2 po = __hfma2(xb, w[3], __hfma2(h0, w[7], __hfma2(h1, w[11], w[15])));
    const __half2 Ti = tanh2(pi, L, NL);
    const __half2 Tf = tanh2(pf, L, NL);
    const __half2 Tg = tanh2(pg, L, NL);
    const __half2 To = tanh2(po, L, NL);
    const __half2 HF = bc(0.5f);
    const __half2 I = __hfma2(Ti, HF, HF);   // sigmoid of raw gate
    const __half2 F = __hfma2(Tf, HF, HF);
    const __half2 O = __hfma2(To, HF, HF);
    c = __hfma2(F, c, __hmul2(I, Tg));
    h = __hmul2(O, tanh2(c, L, NL));
}

// t=0: h=c=0 -> f-gate dead, gates affine in x0.
__device__ __forceinline__ void lstm_t0(__half2 xb, __half2& h, __half2& c,
                                        const __half2* __restrict__ w,
                                        __half2 L, __half2 NL)
{
    const __half2 pi = __hfma2(xb, w[0], w[12]);
    const __half2 pg = __hfma2(xb, w[2], w[14]);
    const __half2 po = __hfma2(xb, w[3], w[15]);
    const __half2 Ti = tanh2(pi, L, NL);
    const __half2 Tg = tanh2(pg, L, NL);
    const __half2 To = tanh2(po, L, NL);
    const __half2 HF = bc(0.5f);
    const __half2 I = __hfma2(Ti, HF, HF);
    const __half2 O = __hfma2(To, HF, HF);
    c = __hmul2(I, Tg);
    h = __hmul2(O, tanh2(c, L, NL));
}

__device__ __forceinline__ float lstm_elem(const float4 xv,
                                           const __half2* __restrict__ w,
                                           float wf0, float wf1, float bf,
                                           __half2 L, __half2 NL)
{
    __half2 h, c;
    lstm_t0(__half2half2(__float2half_rn(xv.x)), h, c, w, L, NL);
    lstm_step(__half2half2(__float2half_rn(xv.y)), h, c, w, L, NL);
    lstm_step(__half2half2(__float2half_rn(xv.z)), h, c, w, L, NL);
    lstm_step(__half2half2(__float2half_rn(xv.w)), h, c, w, L, NL);
    const float h0 = __half2float(__low2half(h));
    const float h1 = __half2float(__high2half(h));
    return fmaf(h0, wf0, fmaf(h1, wf1, bf));
}

__global__ __launch_bounds__(256) void lstm_main(
    const float4* __restrict__ x,     // [B] float4 per element
    const void*   __restrict__ wsv,   // preprocessed constants
    float2* __restrict__ out,         // [B/2]
    int B2)
{
    const int idx = blockIdx.x * blockDim.x + threadIdx.x;
    if (idx >= B2) return;

    const __half2* wg = (const __half2*)wsv;
    const float* wsf = (const float*)((const char*)wsv + 128);

    __half2 w[16];
#pragma unroll
    for (int k = 0; k < 16; ++k) w[k] = wg[k];   // uniform -> scalar loads
    const float wf0 = wsf[0], wf1 = wsf[1], bf = wsf[2];
    const __half2 L = bc(4.0f), NL = bc(-4.0f);

    const float4 xa = x[2 * idx];
    const float4 xb = x[2 * idx + 1];

    const float oa = lstm_elem(xa, w, wf0, wf1, bf, L, NL);
    const float ob = lstm_elem(xb, w, wf0, wf1, bf, L, NL);

    float2 o; o.x = oa; o.y = ob;
    out[idx] = o;
}

extern "C" void kernel_launch(void* const* d_in, const int* in_sizes, int n_in,
                              void* d_out, int out_size, void* d_ws, size_t ws_size,
                              hipStream_t stream)
{
    const float* W_ih = (const float*)d_in[1];
    const float* W_hh = (const float*)d_in[2];
    const float* b_ih = (const float*)d_in[3];
    const float* b_hh = (const float*)d_in[4];
    const float* W_fc = (const float*)d_in[5];
    const float* b_fc = (const float*)d_in[6];

    lstm_prep<<<1, 64, 0, stream>>>(W_ih, W_hh, b_ih, b_hh, W_fc, b_fc, d_ws);

    const float4* x = (const float4*)d_in[0];
    float2* out = (float2*)d_out;
    const int B = in_sizes[0] / 4;   // 4194304
    const int B2 = B / 2;
    const int threads = 256;
    const int blocks = (B2 + threads - 1) / threads;
    lstm_main<<<blocks, threads, 0, stream>>>(x, d_ws, out, B2);
}

// Round 9
// 42.556 us; speedup vs baseline: 1.2078x; 1.2078x over previous
//
#include <hip/hip_runtime.h>
#include <math.h>

// LSTM_8589935226: B=4194304 independent LSTMs, T=4, I=1, H=2, C=1.
// Round 9: activations via LDS lerp tables — ZERO transcendentals, ZERO rcp.
//   tbl[0..1023]    : S(v) = 0.5+0.5*tanh(v), v in [-4,4]    (sigmoid form;
//                     the 0.5 arg-scale is folded into prep weights)
//   tbl[1024..2047] : tanh(w), w in [-8,8]
// Entry = (value, next-value) delta -> lerp = 1 fma. Lookup ~5 V + 1 ds_read.
// Cost model (fit R1..R8): issue = 2V + ~13T. R4 = 2294 cyc/thread;
// this kernel ~1470 -> predict ~28-33 us kernel.

#define GCLAMP 7.9f

// ws float layout: [0..7] wi, [8..15] wh0, [16..23] wh1, [24..31] bb,
// [32..34] fc, [64..4159] tables (1024 float2 SIG, 1024 float2 TANH)
__global__ void lstm_prep(const float* __restrict__ W_ih,
                          const float* __restrict__ W_hh,
                          const float* __restrict__ b_ih,
                          const float* __restrict__ b_hh,
                          const float* __restrict__ W_fc,
                          const float* __restrict__ b_fc,
                          float* __restrict__ ws)
{
    const int k = threadIdx.x;
    if (k < 8) {
        // gate rows: i(0,1) f(2,3) g(4,5) o(6,7); sigmoid rows pre-scaled 0.5
        const float s = (k == 4 || k == 5) ? 1.0f : 0.5f;
        ws[k]      = W_ih[k] * s;
        ws[8 + k]  = W_hh[2 * k] * s;
        ws[16 + k] = W_hh[2 * k + 1] * s;
        ws[24 + k] = (b_ih[k] + b_hh[k]) * s;
    } else if (k == 8) {
        ws[32] = W_fc[0]; ws[33] = W_fc[1]; ws[34] = b_fc[0];
    }
    for (int j = threadIdx.x; j < 1024; j += 256) {
        const float vS = (float)(j - 512) * (1.0f / 128.0f);
        const float s0 = 0.5f + 0.5f * tanhf(vS);
        const float s1 = 0.5f + 0.5f * tanhf(vS + (1.0f / 128.0f));
        ws[64 + 2 * j]     = s0;
        ws[64 + 2 * j + 1] = s1 - s0;
        const float vT = (float)(j - 512) * (1.0f / 64.0f);
        const float t0 = tanhf(vT);
        const float t1 = tanhf(vT + (1.0f / 64.0f));
        ws[64 + 2048 + 2 * j]     = t0;
        ws[64 + 2048 + 2 * j + 1] = t1 - t0;
    }
}

__device__ __forceinline__ float lut(const float2* __restrict__ t, float u) {
    const float fl = floorf(u);
    const float fr = u - fl;
    const int   ii = (int)fl;
    const float2 e = t[ii];
    return fmaf(fr, e.y, e.x);
}

// SIG arg domain [-4,4] -> index 0..1023 ; TANH domain [-8,8] -> 1024..2047
#define SIG(p)   lut(tbl, fmaf((p), 128.0f, 512.0f))
#define TANHL(p) lut(tbl, fmaf((p), 64.0f, 1536.0f))

__device__ __forceinline__ float lstm_elem(const float4 xv,
                                           const float2* __restrict__ tbl,
                                           const float* __restrict__ wi,
                                           const float* __restrict__ wh0,
                                           const float* __restrict__ wh1,
                                           const float* __restrict__ bb,
                                           float wf0, float wf1, float bf)
{
    float h0, h1, c0, c1;

    // ---- t = 0: h=c=0 -> f-gate dead, gates affine in x0 ----
    {
        const float x0 = xv.x;
        const float I0 = SIG(fmaf(x0, wi[0], bb[0]));
        const float I1 = SIG(fmaf(x0, wi[1], bb[1]));
        float pg0 = fmaf(x0, wi[4], bb[4]);
        float pg1 = fmaf(x0, wi[5], bb[5]);
        pg0 = fminf(GCLAMP, fmaxf(-GCLAMP, pg0));
        pg1 = fminf(GCLAMP, fmaxf(-GCLAMP, pg1));
        const float G0 = TANHL(pg0);
        const float G1 = TANHL(pg1);
        const float O0 = SIG(fmaf(x0, wi[6], bb[6]));
        const float O1 = SIG(fmaf(x0, wi[7], bb[7]));
        c0 = I0 * G0;
        c1 = I1 * G1;
        h0 = O0 * TANHL(c0);
        h1 = O1 * TANHL(c1);
    }

    // ---- t = 1..3 ----
    const float xs[3] = {xv.y, xv.z, xv.w};
#pragma unroll
    for (int t = 0; t < 3; ++t) {
        const float xt = xs[t];
        float p0 = fmaf(xt, wi[0], fmaf(h0, wh0[0], fmaf(h1, wh1[0], bb[0])));
        float p1 = fmaf(xt, wi[1], fmaf(h0, wh0[1], fmaf(h1, wh1[1], bb[1])));
        float p2 = fmaf(xt, wi[2], fmaf(h0, wh0[2], fmaf(h1, wh1[2], bb[2])));
        float p3 = fmaf(xt, wi[3], fmaf(h0, wh0[3], fmaf(h1, wh1[3], bb[3])));
        float p4 = fmaf(xt, wi[4], fmaf(h0, wh0[4], fmaf(h1, wh1[4], bb[4])));
        float p5 = fmaf(xt, wi[5], fmaf(h0, wh0[5], fmaf(h1, wh1[5], bb[5])));
        float p6 = fmaf(xt, wi[6], fmaf(h0, wh0[6], fmaf(h1, wh1[6], bb[6])));
        float p7 = fmaf(xt, wi[7], fmaf(h0, wh0[7], fmaf(h1, wh1[7], bb[7])));
        p4 = fminf(GCLAMP, fmaxf(-GCLAMP, p4));
        p5 = fminf(GCLAMP, fmaxf(-GCLAMP, p5));
        const float I0 = SIG(p0), I1 = SIG(p1);
        const float F0 = SIG(p2), F1 = SIG(p3);
        const float G0 = TANHL(p4), G1 = TANHL(p5);
        const float O0 = SIG(p6), O1 = SIG(p7);
        c0 = fmaf(F0, c0, I0 * G0);
        c1 = fmaf(F1, c1, I1 * G1);
        h0 = O0 * TANHL(c0);
        h1 = O1 * TANHL(c1);
    }

    return fmaf(h0, wf0, fmaf(h1, wf1, bf));
}

__global__ __launch_bounds__(256) void lstm_main(
    const float4* __restrict__ x,   // [B] float4 per element
    const float*  __restrict__ ws,  // preprocessed constants + tables
    float2* __restrict__ out,       // [B/2]
    int B2)
{
    __shared__ __align__(16) float2 tbl[2048];
    const int tid = threadIdx.x;

    // cooperative table load: 4096 floats = 1024 float4
    {
        const float4* src = (const float4*)(ws + 64);
        float4* dst = (float4*)tbl;
#pragma unroll
        for (int j = 0; j < 4; ++j) dst[tid + 256 * j] = src[tid + 256 * j];
    }

    // uniform weights -> scalar loads (overlap with table load)
    float wi[8], wh0[8], wh1[8], bb[8];
#pragma unroll
    for (int k = 0; k < 8; ++k) {
        wi[k] = ws[k]; wh0[k] = ws[8 + k]; wh1[k] = ws[16 + k]; bb[k] = ws[24 + k];
    }
    const float wf0 = ws[32], wf1 = ws[33], bf = ws[34];

    __syncthreads();

    const int idx = blockIdx.x * 256 + tid;
    if (idx >= B2) return;

    const float4 xa = x[2 * idx];
    const float4 xb = x[2 * idx + 1];

    const float oa = lstm_elem(xa, tbl, wi, wh0, wh1, bb, wf0, wf1, bf);
    const float ob = lstm_elem(xb, tbl, wi, wh0, wh1, bb, wf0, wf1, bf);

    float2 o; o.x = oa; o.y = ob;
    out[idx] = o;
}

extern "C" void kernel_launch(void* const* d_in, const int* in_sizes, int n_in,
                              void* d_out, int out_size, void* d_ws, size_t ws_size,
                              hipStream_t stream)
{
    const float* W_ih = (const float*)d_in[1];
    const float* W_hh = (const float*)d_in[2];
    const float* b_ih = (const float*)d_in[3];
    const float* b_hh = (const float*)d_in[4];
    const float* W_fc = (const float*)d_in[5];
    const float* b_fc = (const float*)d_in[6];
    float* ws = (float*)d_ws;

    lstm_prep<<<1, 256, 0, stream>>>(W_ih, W_hh, b_ih, b_hh, W_fc, b_fc, ws);

    const float4* x = (const float4*)d_in[0];
    float2* out = (float2*)d_out;
    const int B = in_sizes[0] / 4;   // 4194304
    const int B2 = B / 2;            // 2097152
    const int threads = 256;
    const int blocks = (B2 + threads - 1) / threads;   // 8192
    lstm_main<<<blocks, threads, 0, stream>>>(x, ws, out, B2);
}